// Round 10
// baseline (3954.695 us; speedup 1.0000x reference)
//
#include <hip/hip_runtime.h>

// ---------------------------------------------------------------------------
// MashDecoderV2: 256-layer mamba stack (L=400, D=40) + 65536-query cross-attn
// decoder. f32 throughout (threshold 1.56e-2; current absmax 2e-3).
//
// Round-10: FULLY FUSED STREAMING PIPELINE. One persistent kernel, 462 blocks:
//   blocks 0-255  : layer blocks — byte-identical R8 mamba loop (measured
//                   floor 1739-1750us; do not touch).
//   block 256     : kv block — per chunk: poll layer-255 flag, per-token LN,
//                   kv matvec, agent-scope stores, publish kv_flag (ordered
//                   protocol: stores drained by barrier before flag).
//   blocks 257-461: query blocks — 5 independent waves x 64 queries, no LDS,
//                   no barriers. PE->LN->q in registers (runs during pipeline
//                   fill), then stream kv chunks with online softmax as they
//                   arrive, FFN tail after chunk 99.
//   All 462 blocks are co-resident (2 blocks/CU capacity via
//   __launch_bounds__(320,3): <=170 VGPR, 7.7KB LDS) -> no deadlock possible;
//   worst case (no co-residence) degenerates to R9's serialized schedule.
// ---------------------------------------------------------------------------

#define CH 4
#define NCHUNK 100       // 400 / CH
#define TPB1 320

typedef unsigned long long u64;

__device__ __forceinline__ u64 pack2(float a, float b) {
  return ((u64)__float_as_uint(b) << 32) | (u64)__float_as_uint(a);
}
__device__ __forceinline__ float unplo(u64 a) {
  return __uint_as_float((unsigned)a);
}
__device__ __forceinline__ float unphi(u64 a) {
  return __uint_as_float((unsigned)(a >> 32));
}

__global__ void init_flags(int* __restrict__ flags) {
  int i = blockIdx.x * 256 + threadIdx.x;
  if (i < 257 * 16) flags[i] = 0;
}

__global__ __launch_bounds__(TPB1, 3) void mamba_pipe(
    const float* __restrict__ mash,
    const float* __restrict__ g_norm_w,   // (256,40)
    const float* __restrict__ g_in_w,     // (256,160,40)
    const float* __restrict__ g_conv_w,   // (256,80,4)
    const float* __restrict__ g_conv_b,   // (256,80)
    const float* __restrict__ g_xp_w,     // (256,35,80)
    const float* __restrict__ g_dt_w,     // (256,80,3)
    const float* __restrict__ g_dt_b,     // (256,80)
    const float* __restrict__ g_alog,     // (256,80,16)
    const float* __restrict__ g_D,        // (256,80)
    const float* __restrict__ g_out_w,    // (256,40,80)
    float* __restrict__ xb0,
    float* __restrict__ xb1,
    int* __restrict__ flags,
    // kv block
    const float* __restrict__ lnc_w, const float* __restrict__ lnc_b,
    const float* __restrict__ kv_w,
    float* __restrict__ kbuf, float* __restrict__ vbuf,
    // query blocks
    const float* __restrict__ qry,
    const float* __restrict__ pe_w, const float* __restrict__ pe_b,
    const float* __restrict__ lnq_w, const float* __restrict__ lnq_b,
    const float* __restrict__ qw,
    const float* __restrict__ ow, const float* __restrict__ ob,
    const float* __restrict__ flw, const float* __restrict__ flb,
    const float* __restrict__ w1, const float* __restrict__ b1,
    const float* __restrict__ w2, const float* __restrict__ b2,
    const float* __restrict__ outw, const float* __restrict__ outb,
    float* __restrict__ out)
{
  const int tid = threadIdx.x;

  // shared (layer blocks; kv block reuses xz and yb)
  __shared__ float xin[160];
  __shared__ float xz[640];
  __shared__ float xs[320];
  __shared__ float dbc[144];        // stride 36
  __shared__ float yb[320];
  __shared__ float xhist[240];      // conv tail

  // =================== QUERY BLOCKS (257..461) ===========================
  if (blockIdx.x >= 257) {
    const int waveid = tid >> 6;
    const int lane = tid & 63;
    const int wq = (blockIdx.x - 257) * 5 + waveid;
    if (wq >= 1024) return;
    const int n = wq * 64 + lane;

    // ---- PE-MLP -> LN -> q (registers; runs during pipeline fill) ----
    const float qx = qry[n * 3 + 0], qy = qry[n * 3 + 1], qz = qry[n * 3 + 2];
    float q[40];
    {
      float qe[40];
#pragma unroll
      for (int d = 0; d < 40; ++d) qe[d] = pe_b[d];
#pragma unroll 1
      for (int j = 0; j < 8; ++j) {
        float f = 3.14159265358979323846f * (float)(1 << j);
        float sx, cx, sy, cy, sz, cz;
        __sincosf(qx * f, &sx, &cx);
        __sincosf(qy * f, &sy, &cy);
        __sincosf(qz * f, &sz, &cz);
#pragma unroll
        for (int d = 0; d < 40; ++d) {
          const float* r = pe_w + d * 51;
          qe[d] += sx * r[j] + sy * r[j + 8] + sz * r[j + 16]
                 + cx * r[j + 24] + cy * r[j + 32] + cz * r[j + 40];
        }
      }
#pragma unroll
      for (int d = 0; d < 40; ++d) {
        const float* r = pe_w + d * 51;
        qe[d] += qx * r[48] + qy * r[49] + qz * r[50];
      }
      float m = 0.f;
#pragma unroll
      for (int d = 0; d < 40; ++d) m += qe[d];
      m *= (1.f / 40.f);
      float var = 0.f;
#pragma unroll
      for (int d = 0; d < 40; ++d) { float dv = qe[d] - m; var += dv * dv; }
      float rstd = rsqrtf(var * (1.f / 40.f) + 1e-5f);
      float qn[40];
#pragma unroll
      for (int d = 0; d < 40; ++d)
        qn[d] = (qe[d] - m) * rstd * lnq_w[d] + lnq_b[d];
#pragma unroll
      for (int e = 0; e < 40; ++e) {
        const float* r = qw + e * 40;
        float s = 0.f;
#pragma unroll
        for (int d = 0; d < 40; ++d) s += qn[d] * r[d];
        q[e] = s;
      }
    }

    // ---- streaming flash attention over kv chunks as they arrive ----
    int* kv_flag = flags + 256 * 16;
    float acc[40];
#pragma unroll
    for (int d = 0; d < 40; ++d) acc[d] = 0.f;
    float mx = -1e30f, l = 0.f;
    const float scale = 0.15811388300841897f;  // 40^-0.5
#pragma unroll 1
    for (int c = 0; c < NCHUNK; ++c) {
      if (c == 0) {
        while (__hip_atomic_load(kv_flag, __ATOMIC_RELAXED,
                                 __HIP_MEMORY_SCOPE_AGENT) <= 0)
          __builtin_amdgcn_s_sleep(32);
      } else {
        while (__hip_atomic_load(kv_flag, __ATOMIC_RELAXED,
                                 __HIP_MEMORY_SCOPE_AGENT) <= c)
          __builtin_amdgcn_s_sleep(8);
      }
#pragma unroll 1
      for (int tt = 0; tt < CH; ++tt) {
        const int t = c * CH + tt;
        const u64* kp = (const u64*)(kbuf + t * 40);
        float kvv[40];
#pragma unroll
        for (int k = 0; k < 20; ++k) {
          u64 a = __hip_atomic_load(kp + k, __ATOMIC_RELAXED,
                                    __HIP_MEMORY_SCOPE_AGENT);
          kvv[2 * k] = unplo(a); kvv[2 * k + 1] = unphi(a);
        }
        float s0 = 0.f, s1 = 0.f, s2 = 0.f, s3 = 0.f;
#pragma unroll
        for (int d = 0; d < 40; d += 4) {
          s0 += q[d] * kvv[d]; s1 += q[d + 1] * kvv[d + 1];
          s2 += q[d + 2] * kvv[d + 2]; s3 += q[d + 3] * kvv[d + 3];
        }
        float s = ((s0 + s1) + (s2 + s3)) * scale;
        if (s > mx) {
          float corr = __expf(mx - s);
          l *= corr;
#pragma unroll
          for (int d = 0; d < 40; ++d) acc[d] *= corr;
          mx = s;
        }
        float p = __expf(s - mx);
        l += p;
        const u64* vp = (const u64*)(vbuf + t * 40);
#pragma unroll
        for (int k = 0; k < 20; ++k) {
          u64 a = __hip_atomic_load(vp + k, __ATOMIC_RELAXED,
                                    __HIP_MEMORY_SCOPE_AGENT);
          acc[2 * k] += p * unplo(a);
          acc[2 * k + 1] += p * unphi(a);
        }
      }
    }

    // ---- tail: lat2 -> LN -> FFN -> out ----
    float linv = 1.f / l;
    float lat[40];
#pragma unroll
    for (int d = 0; d < 40; ++d) lat[d] = acc[d] * linv;
    float lat2[40];
#pragma unroll 1
    for (int e = 0; e < 40; ++e) {
      const float* r = ow + e * 40;
      float s = 0.f;
#pragma unroll
      for (int d = 0; d < 40; ++d) s += lat[d] * r[d];
      lat2[e] = ob[e] + s;
    }
    float hh[40];
    {
      float m = 0.f;
#pragma unroll
      for (int d = 0; d < 40; ++d) m += lat2[d];
      m *= (1.f / 40.f);
      float var = 0.f;
#pragma unroll
      for (int d = 0; d < 40; ++d) { float dv = lat2[d] - m; var += dv * dv; }
      float rstd = rsqrtf(var * (1.f / 40.f) + 1e-5f);
#pragma unroll
      for (int d = 0; d < 40; ++d)
        hh[d] = (lat2[d] - m) * rstd * flw[d] + flb[d];
    }
    float ff[40];
#pragma unroll
    for (int d = 0; d < 40; ++d) ff[d] = b2[d];
#pragma unroll 1
    for (int e = 0; e < 160; ++e) {
      const float* r1 = w1 + e * 40;
      const float* r2 = w1 + (160 + e) * 40;
      float a0 = 0.f, a1 = 0.f;
#pragma unroll
      for (int d = 0; d < 40; ++d) { a0 += hh[d] * r1[d]; a1 += hh[d] * r2[d]; }
      float x1 = a0 + b1[e];
      float g = a1 + b1[160 + e];
      float tv = x1 * (0.5f * g * (1.f + erff(g * 0.70710678118654752f)));
#pragma unroll
      for (int d = 0; d < 40; ++d) ff[d] += tv * w2[d * 160 + e];
    }
    float r = outb[0];
#pragma unroll
    for (int d = 0; d < 40; ++d) r += (lat2[d] + ff[d]) * outw[d];
    out[n] = r;
    return;
  }

  // =================== KV BLOCK (256) ====================================
  if (blockIdx.x == 256) {
    const int t_k = tid / 80;          // token in chunk
    const int e_k = tid % 80;          // kv output index
    float wkv[40];
    {
      const float4* g = (const float4*)(kv_w + e_k * 40);
#pragma unroll
      for (int k = 0; k < 10; ++k) {
        float4 v = g[k];
        wkv[4 * k] = v.x; wkv[4 * k + 1] = v.y;
        wkv[4 * k + 2] = v.z; wkv[4 * k + 3] = v.w;
      }
    }
    float lw = 0.f, lb = 0.f;
    if (tid < 160) { lw = lnc_w[tid % 40]; lb = lnc_b[tid % 40]; }
    const u64* srcT = (const u64*)xb1;   // layer 255 (odd) writes xb1
    int* flag_src = flags + 255 * 16;
    int* kv_flag = flags + 256 * 16;

    for (int c = 0; c < NCHUNK; ++c) {
      while (__hip_atomic_load(flag_src, __ATOMIC_RELAXED,
                               __HIP_MEMORY_SCOPE_AGENT) <= c)
        __builtin_amdgcn_s_sleep(1);
      if (tid < 80) {
        u64 a = __hip_atomic_load(srcT + c * 80 + tid, __ATOMIC_RELAXED,
                                  __HIP_MEMORY_SCOPE_AGENT);
        xz[2 * tid] = unplo(a);
        xz[2 * tid + 1] = unphi(a);
      }
      __syncthreads();                     // x chunk in xz[0..160)
      if (tid < 160) {
        const int t = tid / 40;
        float m = 0.f;
#pragma unroll
        for (int k = 0; k < 40; ++k) m += xz[t * 40 + k];
        m *= (1.f / 40.f);
        float var = 0.f;
#pragma unroll
        for (int k = 0; k < 40; ++k) {
          float dv = xz[t * 40 + k] - m; var += dv * dv;
        }
        float rstd = rsqrtf(var * (1.f / 40.f) + 1e-5f);
        yb[tid] = (xz[tid] - m) * rstd * lw + lb;   // cn
      }
      __syncthreads();                     // cn in yb[0..160)
      {
        const float* cn = &yb[t_k * 40];
        float s = 0.f;
#pragma unroll
        for (int d = 0; d < 40; ++d) s += wkv[d] * cn[d];
        const int trow = c * CH + t_k;
        if (e_k < 40)
          __hip_atomic_store(&kbuf[trow * 40 + e_k], s, __ATOMIC_RELAXED,
                             __HIP_MEMORY_SCOPE_AGENT);
        else
          __hip_atomic_store(&vbuf[trow * 40 + (e_k - 40)], s,
                             __ATOMIC_RELAXED, __HIP_MEMORY_SCOPE_AGENT);
      }
      __syncthreads();                     // drain vmcnt (stores at IF$)
      if (tid == 0)
        __hip_atomic_store(kv_flag, c + 1, __ATOMIC_RELAXED,
                           __HIP_MEMORY_SCOPE_AGENT);
    }
    return;
  }

  // =================== LAYER BLOCKS (0..255): R8 loop, unchanged =========
  const int layer = blockIdx.x;

  const int e_in = tid % 160;
  const int tA = tid / 160;
  float w_in_r[40];                 // in_proj row with rmsnorm weight folded
  {
    const float4* g = (const float4*)(g_in_w + layer * 6400 + e_in * 40);
    const float4* nw = (const float4*)(g_norm_w + layer * 40);
#pragma unroll
    for (int k = 0; k < 10; ++k) {
      float4 v = g[k];
      float4 n = nw[k];
      w_in_r[4 * k] = v.x * n.x; w_in_r[4 * k + 1] = v.y * n.y;
      w_in_r[4 * k + 2] = v.z * n.z; w_in_r[4 * k + 3] = v.w * n.w;
    }
  }
  const int d_c = tid % 80;
  const int t_c = tid / 80;
  float cw[4]; float cb;
  {
    float4 v = *(const float4*)(g_conv_w + layer * 320 + d_c * 4);
    cw[0] = v.x; cw[1] = v.y; cw[2] = v.z; cw[3] = v.w;
    cb = g_conv_b[layer * 80 + d_c];
  }
  const int halfp = tid & 1;
  const int p_x = tid >> 1;              // <140 active for x_proj
  const int t_x = p_x / 35, e_x = p_x % 35;
  float w_xp_r[40];
  if (p_x < 140) {
    const float4* g = (const float4*)(g_xp_w + layer * 2800 + e_x * 80 + halfp * 40);
#pragma unroll
    for (int k = 0; k < 10; ++k) {
      float4 v = g[k];
      w_xp_r[4 * k] = v.x; w_xp_r[4 * k + 1] = v.y;
      w_xp_r[4 * k + 2] = v.z; w_xp_r[4 * k + 3] = v.w;
    }
  }
  const int d_ch = tid >> 2;
  const int qq = tid & 3;
  float negA[4], hst[4];
  {
    float4 v = *(const float4*)(g_alog + layer * 1280 + tid * 4);
    negA[0] = -__expf(v.x); negA[1] = -__expf(v.y);
    negA[2] = -__expf(v.z); negA[3] = -__expf(v.w);
    hst[0] = hst[1] = hst[2] = hst[3] = 0.f;
  }
  const float dtw0 = g_dt_w[layer * 240 + d_ch * 3 + 0];
  const float dtw1 = g_dt_w[layer * 240 + d_ch * 3 + 1];
  const float dtw2 = g_dt_w[layer * 240 + d_ch * 3 + 2];
  const float dtb = g_dt_b[layer * 80 + d_ch];
  const float wD = g_D[layer * 80 + d_ch];
  const int p_o = tid >> 1;
  const int t_o = p_o / 40, e_o = p_o % 40;
  float w_out_r[40];
  {
    const float4* g = (const float4*)(g_out_w + layer * 3200 + e_o * 80 + halfp * 40);
#pragma unroll
    for (int k = 0; k < 10; ++k) {
      float4 v = g[k];
      w_out_r[4 * k] = v.x; w_out_r[4 * k + 1] = v.y;
      w_out_r[4 * k + 2] = v.z; w_out_r[4 * k + 3] = v.w;
    }
  }

  for (int i = tid; i < 240; i += TPB1) xhist[i] = 0.f;
  __syncthreads();

  const float* src = (layer == 0) ? mash : ((layer & 1) ? xb0 : xb1);
  float* dst = (layer & 1) ? xb1 : xb0;
  int* flag_prev = flags + (layer - 1) * 16;
  int* flag_cur = flags + layer * 16;

  for (int c = 0; c < NCHUNK; ++c) {
    const int t0 = c * CH;

    // ---- Phase A: ordered acquire + in_proj (rmsnorm folded) ----
    if (layer == 0) {
#pragma unroll
      for (int tt = 0; tt < 2; ++tt) {
        const int t = tA + 2 * tt;
        const float4* sp = (const float4*)(src + (t0 + t) * 40);
        float ss = 0.f, sd = 0.f;
#pragma unroll
        for (int k = 0; k < 10; ++k) {
          float4 v = sp[k];
          ss += v.x * v.x + v.y * v.y + v.z * v.z + v.w * v.w;
          sd += w_in_r[4 * k] * v.x + w_in_r[4 * k + 1] * v.y
              + w_in_r[4 * k + 2] * v.z + w_in_r[4 * k + 3] * v.w;
        }
        xz[t * 160 + e_in] = sd * rsqrtf(ss * (1.f / 40.f) + 1e-5f);
      }
      if (tid < 160) xin[tid] = src[t0 * 40 + tid];
    } else {
      // every wave polls (wave-uniform); loads are program-ordered after the
      // observed flag -> guaranteed fresh (producer B5-drained before flag)
      while (__hip_atomic_load(flag_prev, __ATOMIC_RELAXED,
                               __HIP_MEMORY_SCOPE_AGENT) <= c)
        __builtin_amdgcn_s_sleep(1);
#pragma unroll
      for (int tt = 0; tt < 2; ++tt) {
        const int t = tA + 2 * tt;
        const u64* sp = (const u64*)(src + (t0 + t) * 40);
        float ss = 0.f, sd = 0.f;
#pragma unroll
        for (int k = 0; k < 20; ++k) {
          u64 a = __hip_atomic_load(sp + k, __ATOMIC_RELAXED,
                                    __HIP_MEMORY_SCOPE_AGENT);
          float v0 = unplo(a), v1 = unphi(a);
          ss += v0 * v0 + v1 * v1;
          sd += w_in_r[2 * k] * v0 + w_in_r[2 * k + 1] * v1;
        }
        xz[t * 160 + e_in] = sd * rsqrtf(ss * (1.f / 40.f) + 1e-5f);
      }
      if (tid < 80) {
        u64 a = __hip_atomic_load((const u64*)(src + t0 * 40) + tid,
                                  __ATOMIC_RELAXED, __HIP_MEMORY_SCOPE_AGENT);
        xin[2 * tid] = unplo(a);
        xin[2 * tid + 1] = unphi(a);
      }
    }
    __syncthreads();                                   // B1: xz, xin ready

    // ---- causal depthwise conv(4) + silu ----
    {
      float acc = cb;
#pragma unroll
      for (int j = 0; j < 4; ++j) {
        int lt = t_c - 3 + j;
        float xv = (lt >= 0) ? xz[lt * 160 + d_c] : xhist[(lt + 3) * 80 + d_c];
        acc += cw[j] * xv;
      }
      xs[t_c * 80 + d_c] = acc / (1.f + __expf(-acc));
    }
    __syncthreads();                                   // B2: xs ready

    // ---- x_proj: pair half-dots + shfl merge; idle threads refresh xhist ----
    if (p_x < 140) {
      const float4* xp = (const float4*)&xs[t_x * 80 + halfp * 40];
      float s = 0.f;
#pragma unroll
      for (int k = 0; k < 10; ++k) {
        float4 v = xp[k];
        s += w_xp_r[4 * k] * v.x + w_xp_r[4 * k + 1] * v.y
           + w_xp_r[4 * k + 2] * v.z + w_xp_r[4 * k + 3] * v.w;
      }
      s += __shfl_xor(s, 1);
      if (halfp == 0) dbc[t_x * 36 + e_x] = s;
    } else {
      for (int k = tid - 280; k < 240; k += 40)
        xhist[k] = xz[(1 + k / 80) * 160 + (k % 80)];
    }
    __syncthreads();                                   // B3: dbc ready

    // ---- selective scan; dt inline; state in regs ----
#pragma unroll
    for (int t = 0; t < CH; ++t) {
      const float* db = &dbc[t * 36];
      float sdt = dtb + db[0] * dtw0 + db[1] * dtw1 + db[2] * dtw2;
      float dtval = (sdt > 15.f) ? sdt : __logf(1.f + __expf(sdt));
      float xval = xs[t * 80 + d_ch];
      float part = 0.f;
#pragma unroll
      for (int j = 0; j < 4; ++j) {
        int s_i = qq * 4 + j;
        float Bv = db[3 + s_i];
        float Cv = db[19 + s_i];
        hst[j] = __expf(dtval * negA[j]) * hst[j] + dtval * Bv * xval;
        part += hst[j] * Cv;
      }
      part += __shfl_xor(part, 1);
      part += __shfl_xor(part, 2);
      if (qq == 0) {
        float yv = part + xval * wD;
        float z = xz[t * 160 + 80 + d_ch];
        yb[t * 80 + d_ch] = yv * z / (1.f + __expf(-z));
      }
    }
    __syncthreads();                                   // B4: yb ready

    // ---- out_proj + residual -> paired dwordx2 coherent stores ----
    {
      const float4* yp = (const float4*)&yb[t_o * 80 + halfp * 40];
      float s = 0.f;
#pragma unroll
      for (int k = 0; k < 10; ++k) {
        float4 v = yp[k];
        s += w_out_r[4 * k] * v.x + w_out_r[4 * k + 1] * v.y
           + w_out_r[4 * k + 2] * v.z + w_out_r[4 * k + 3] * v.w;
      }
      s += __shfl_xor(s, 1);
      float r = xin[p_o] + s;          // valid on pair leaders (halfp==0)
      float r2 = __shfl_xor(r, 2);     // leader tid+2's value (p_o+1)
      if ((tid & 3) == 0)              // even p_o leaders store the pair
        __hip_atomic_store((u64*)(dst + t0 * 40 + p_o), pack2(r, r2),
                           __ATOMIC_RELAXED, __HIP_MEMORY_SCOPE_AGENT);
    }
    __syncthreads();        // B5: drains vmcnt -> all stores acked at IF$
    if (tid == 0)
      __hip_atomic_store(flag_cur, c + 1, __ATOMIC_RELAXED,
                         __HIP_MEMORY_SCOPE_AGENT);
  }
}

extern "C" void kernel_launch(void* const* d_in, const int* in_sizes, int n_in,
                              void* d_out, int out_size, void* d_ws, size_t ws_size,
                              hipStream_t stream) {
  const float* mash   = (const float*)d_in[0];
  const float* qry    = (const float*)d_in[1];
  const float* lnw    = (const float*)d_in[2];
  const float* linw   = (const float*)d_in[3];
  const float* lconvw = (const float*)d_in[4];
  const float* lconvb = (const float*)d_in[5];
  const float* lxpw   = (const float*)d_in[6];
  const float* ldtw   = (const float*)d_in[7];
  const float* ldtb   = (const float*)d_in[8];
  const float* lAlog  = (const float*)d_in[9];
  const float* lD     = (const float*)d_in[10];
  const float* loutw  = (const float*)d_in[11];
  const float* pew    = (const float*)d_in[12];
  const float* peb    = (const float*)d_in[13];
  const float* lnqw   = (const float*)d_in[14];
  const float* lnqb   = (const float*)d_in[15];
  const float* lncw   = (const float*)d_in[16];
  const float* lncb   = (const float*)d_in[17];
  const float* qw     = (const float*)d_in[18];
  const float* kvw    = (const float*)d_in[19];
  const float* oww    = (const float*)d_in[20];
  const float* owb    = (const float*)d_in[21];
  const float* flnw   = (const float*)d_in[22];
  const float* flnb   = (const float*)d_in[23];
  const float* w1     = (const float*)d_in[24];
  const float* b1     = (const float*)d_in[25];
  const float* w2     = (const float*)d_in[26];
  const float* b2     = (const float*)d_in[27];
  const float* outw   = (const float*)d_in[28];
  const float* outb   = (const float*)d_in[29];

  // ws layout (f32): xb0[16000] xb1[16000] k[16000] v[16000] flags[257*16]
  float* wsf = (float*)d_ws;
  float* xb0 = wsf;
  float* xb1 = wsf + 16000;
  float* kbuf = wsf + 32000;
  float* vbuf = wsf + 48000;
  int* flags = (int*)(wsf + 64000);

  hipLaunchKernelGGL(init_flags, dim3(17), dim3(256), 0, stream, flags);
  hipLaunchKernelGGL(mamba_pipe, dim3(462), dim3(TPB1), 0, stream,
                     mash, lnw, linw, lconvw, lconvb, lxpw, ldtw, ldtb, lAlog,
                     lD, loutw, xb0, xb1, flags,
                     lncw, lncb, kvw, kbuf, vbuf,
                     qry, pew, peb, lnqw, lnqb, qw,
                     oww, owb, flnw, flnb, w1, b1, w2, b2, outw, outb,
                     (float*)d_out);
}

// Round 11
// 2352.595 us; speedup vs baseline: 1.6810x; 1.6810x over previous
//
#include <hip/hip_runtime.h>

// ---------------------------------------------------------------------------
// MashDecoderV2: 256-layer mamba stack (L=400, D=40) + 65536-query cross-attn
// decoder. f32 throughout (threshold 1.56e-2; current absmax 2e-3).
//
// Round-11: fused streaming pipeline, R10 retried with its two failure causes
// removed (R10 was CORRECT but slow):
//   - NO launch_bounds min-waves cap (R10's ",3" forced VGPR 116->84 =>
//     stationary-weight spills => +29MB scratch traffic, T_stage 4.9->11us).
//     Worst case if VGPR>170: query blocks lose co-residency and simply run
//     after the layers (serialized ~ R9; deadlock impossible since all waits
//     point to lower, earlier-dispatched block ids).
//   - BATCHED polling: query blocks consume kv in 5 batches of 20 chunks;
//     only tid==0 polls (s_sleep(32) cadence), other waves parked at a
//     barrier. R10 had 1025 waves spinning per-chunk on one IF$ line.
//   - Flags padded to 128B stride (adjacent-layer polls shared a line).
// Blocks: 0-255 layer (R8 loop, byte-identical); 256 kv; 257-461 query
// (5 waves x 64 queries each; PE->LN->q in regs during fill; streaming
// online-softmax; FFN tail). All verified correct in R10.
// ---------------------------------------------------------------------------

#define CH 4
#define NCHUNK 100       // 400 / CH
#define TPB1 320

typedef unsigned long long u64;

__device__ __forceinline__ u64 pack2(float a, float b) {
  return ((u64)__float_as_uint(b) << 32) | (u64)__float_as_uint(a);
}
__device__ __forceinline__ float unplo(u64 a) {
  return __uint_as_float((unsigned)a);
}
__device__ __forceinline__ float unphi(u64 a) {
  return __uint_as_float((unsigned)(a >> 32));
}

__global__ void init_flags(int* __restrict__ flags) {
  int i = blockIdx.x * 256 + threadIdx.x;
  if (i < 258 * 32) flags[i] = 0;
}

__global__ __launch_bounds__(TPB1) void mamba_pipe(
    const float* __restrict__ mash,
    const float* __restrict__ g_norm_w,   // (256,40)
    const float* __restrict__ g_in_w,     // (256,160,40)
    const float* __restrict__ g_conv_w,   // (256,80,4)
    const float* __restrict__ g_conv_b,   // (256,80)
    const float* __restrict__ g_xp_w,     // (256,35,80)
    const float* __restrict__ g_dt_w,     // (256,80,3)
    const float* __restrict__ g_dt_b,     // (256,80)
    const float* __restrict__ g_alog,     // (256,80,16)
    const float* __restrict__ g_D,        // (256,80)
    const float* __restrict__ g_out_w,    // (256,40,80)
    float* __restrict__ xb0,
    float* __restrict__ xb1,
    int* __restrict__ flags,              // stride 32 ints (128B) per flag
    // kv block
    const float* __restrict__ lnc_w, const float* __restrict__ lnc_b,
    const float* __restrict__ kv_w,
    float* __restrict__ kbuf, float* __restrict__ vbuf,
    // query blocks
    const float* __restrict__ qry,
    const float* __restrict__ pe_w, const float* __restrict__ pe_b,
    const float* __restrict__ lnq_w, const float* __restrict__ lnq_b,
    const float* __restrict__ qw,
    const float* __restrict__ ow, const float* __restrict__ ob,
    const float* __restrict__ flw, const float* __restrict__ flb,
    const float* __restrict__ w1, const float* __restrict__ b1,
    const float* __restrict__ w2, const float* __restrict__ b2,
    const float* __restrict__ outw, const float* __restrict__ outb,
    float* __restrict__ out)
{
  const int tid = threadIdx.x;

  // shared (layer blocks; kv block reuses xz and yb; query blocks unused)
  __shared__ float xin[160];
  __shared__ float xz[640];
  __shared__ float xs[320];
  __shared__ float dbc[144];        // stride 36
  __shared__ float yb[320];
  __shared__ float xhist[240];      // conv tail

  // =================== QUERY BLOCKS (257..461) ===========================
  if (blockIdx.x >= 257) {
    const int waveid = tid >> 6;
    const int lane = tid & 63;
    const int wq = (blockIdx.x - 257) * 5 + waveid;
    const bool qvalid = (wq < 1024);
    const int n = qvalid ? (wq * 64 + lane) : 65535;

    // ---- PE-MLP -> LN -> q (registers; runs during pipeline fill) ----
    const float qx = qry[n * 3 + 0], qy = qry[n * 3 + 1], qz = qry[n * 3 + 2];
    float q[40];
    {
      float qe[40];
#pragma unroll
      for (int d = 0; d < 40; ++d) qe[d] = pe_b[d];
#pragma unroll 1
      for (int j = 0; j < 8; ++j) {
        float f = 3.14159265358979323846f * (float)(1 << j);
        float sx, cx, sy, cy, sz, cz;
        __sincosf(qx * f, &sx, &cx);
        __sincosf(qy * f, &sy, &cy);
        __sincosf(qz * f, &sz, &cz);
#pragma unroll
        for (int d = 0; d < 40; ++d) {
          const float* r = pe_w + d * 51;
          qe[d] += sx * r[j] + sy * r[j + 8] + sz * r[j + 16]
                 + cx * r[j + 24] + cy * r[j + 32] + cz * r[j + 40];
        }
      }
#pragma unroll
      for (int d = 0; d < 40; ++d) {
        const float* r = pe_w + d * 51;
        qe[d] += qx * r[48] + qy * r[49] + qz * r[50];
      }
      float m = 0.f;
#pragma unroll
      for (int d = 0; d < 40; ++d) m += qe[d];
      m *= (1.f / 40.f);
      float var = 0.f;
#pragma unroll
      for (int d = 0; d < 40; ++d) { float dv = qe[d] - m; var += dv * dv; }
      float rstd = rsqrtf(var * (1.f / 40.f) + 1e-5f);
      float qn[40];
#pragma unroll
      for (int d = 0; d < 40; ++d)
        qn[d] = (qe[d] - m) * rstd * lnq_w[d] + lnq_b[d];
#pragma unroll
      for (int e = 0; e < 40; ++e) {
        const float* r = qw + e * 40;
        float s = 0.f;
#pragma unroll
        for (int d = 0; d < 40; ++d) s += qn[d] * r[d];
        q[e] = s;
      }
    }

    // ---- streaming flash attention: 5 batches of 20 chunks (80 tokens) ----
    int* kv_flag = flags + 256 * 32;
    float acc[40];
#pragma unroll
    for (int d = 0; d < 40; ++d) acc[d] = 0.f;
    float mx = -1e30f, l = 0.f;
    const float scale = 0.15811388300841897f;  // 40^-0.5
#pragma unroll 1
    for (int b = 0; b < 5; ++b) {
      // single poller per block; other waves park at the barrier (no issue)
      if (tid == 0) {
        const int ctarget = (b + 1) * 20;
        while (__hip_atomic_load(kv_flag, __ATOMIC_RELAXED,
                                 __HIP_MEMORY_SCOPE_AGENT) < ctarget)
          __builtin_amdgcn_s_sleep(32);
      }
      __syncthreads();
#pragma unroll 1
      for (int t = b * 80; t < b * 80 + 80; ++t) {
        const u64* kp = (const u64*)(kbuf + t * 40);
        float kvv[40];
#pragma unroll
        for (int k = 0; k < 20; ++k) {
          u64 a = __hip_atomic_load(kp + k, __ATOMIC_RELAXED,
                                    __HIP_MEMORY_SCOPE_AGENT);
          kvv[2 * k] = unplo(a); kvv[2 * k + 1] = unphi(a);
        }
        float s0 = 0.f, s1 = 0.f, s2 = 0.f, s3 = 0.f;
#pragma unroll
        for (int d = 0; d < 40; d += 4) {
          s0 += q[d] * kvv[d]; s1 += q[d + 1] * kvv[d + 1];
          s2 += q[d + 2] * kvv[d + 2]; s3 += q[d + 3] * kvv[d + 3];
        }
        float s = ((s0 + s1) + (s2 + s3)) * scale;
        if (s > mx) {
          float corr = __expf(mx - s);
          l *= corr;
#pragma unroll
          for (int d = 0; d < 40; ++d) acc[d] *= corr;
          mx = s;
        }
        float p = __expf(s - mx);
        l += p;
        const u64* vp = (const u64*)(vbuf + t * 40);
#pragma unroll
        for (int k = 0; k < 20; ++k) {
          u64 a = __hip_atomic_load(vp + k, __ATOMIC_RELAXED,
                                    __HIP_MEMORY_SCOPE_AGENT);
          acc[2 * k] += p * unplo(a);
          acc[2 * k + 1] += p * unphi(a);
        }
      }
    }

    // ---- tail: lat2 -> LN -> FFN -> out ----
    float linv = 1.f / l;
    float lat[40];
#pragma unroll
    for (int d = 0; d < 40; ++d) lat[d] = acc[d] * linv;
    float lat2[40];
#pragma unroll 1
    for (int e = 0; e < 40; ++e) {
      const float* r = ow + e * 40;
      float s = 0.f;
#pragma unroll
      for (int d = 0; d < 40; ++d) s += lat[d] * r[d];
      lat2[e] = ob[e] + s;
    }
    float hh[40];
    {
      float m = 0.f;
#pragma unroll
      for (int d = 0; d < 40; ++d) m += lat2[d];
      m *= (1.f / 40.f);
      float var = 0.f;
#pragma unroll
      for (int d = 0; d < 40; ++d) { float dv = lat2[d] - m; var += dv * dv; }
      float rstd = rsqrtf(var * (1.f / 40.f) + 1e-5f);
#pragma unroll
      for (int d = 0; d < 40; ++d)
        hh[d] = (lat2[d] - m) * rstd * flw[d] + flb[d];
    }
    float ff[40];
#pragma unroll
    for (int d = 0; d < 40; ++d) ff[d] = b2[d];
#pragma unroll 1
    for (int e = 0; e < 160; ++e) {
      const float* r1 = w1 + e * 40;
      const float* r2 = w1 + (160 + e) * 40;
      float a0 = 0.f, a1 = 0.f;
#pragma unroll
      for (int d = 0; d < 40; ++d) { a0 += hh[d] * r1[d]; a1 += hh[d] * r2[d]; }
      float x1 = a0 + b1[e];
      float g = a1 + b1[160 + e];
      float tv = x1 * (0.5f * g * (1.f + erff(g * 0.70710678118654752f)));
#pragma unroll
      for (int d = 0; d < 40; ++d) ff[d] += tv * w2[d * 160 + e];
    }
    float r = outb[0];
#pragma unroll
    for (int d = 0; d < 40; ++d) r += (lat2[d] + ff[d]) * outw[d];
    if (qvalid) out[n] = r;
    return;
  }

  // =================== KV BLOCK (256) ====================================
  if (blockIdx.x == 256) {
    const int t_k = tid / 80;          // token in chunk
    const int e_k = tid % 80;          // kv output index
    float wkv[40];
    {
      const float4* g = (const float4*)(kv_w + e_k * 40);
#pragma unroll
      for (int k = 0; k < 10; ++k) {
        float4 v = g[k];
        wkv[4 * k] = v.x; wkv[4 * k + 1] = v.y;
        wkv[4 * k + 2] = v.z; wkv[4 * k + 3] = v.w;
      }
    }
    float lw = 0.f, lb = 0.f;
    if (tid < 160) { lw = lnc_w[tid % 40]; lb = lnc_b[tid % 40]; }
    const u64* srcT = (const u64*)xb1;   // layer 255 (odd) writes xb1
    int* flag_src = flags + 255 * 32;
    int* kv_flag = flags + 256 * 32;

    for (int c = 0; c < NCHUNK; ++c) {
      while (__hip_atomic_load(flag_src, __ATOMIC_RELAXED,
                               __HIP_MEMORY_SCOPE_AGENT) <= c)
        __builtin_amdgcn_s_sleep(1);
      if (tid < 80) {
        u64 a = __hip_atomic_load(srcT + c * 80 + tid, __ATOMIC_RELAXED,
                                  __HIP_MEMORY_SCOPE_AGENT);
        xz[2 * tid] = unplo(a);
        xz[2 * tid + 1] = unphi(a);
      }
      __syncthreads();                     // x chunk in xz[0..160)
      if (tid < 160) {
        const int t = tid / 40;
        float m = 0.f;
#pragma unroll
        for (int k = 0; k < 40; ++k) m += xz[t * 40 + k];
        m *= (1.f / 40.f);
        float var = 0.f;
#pragma unroll
        for (int k = 0; k < 40; ++k) {
          float dv = xz[t * 40 + k] - m; var += dv * dv;
        }
        float rstd = rsqrtf(var * (1.f / 40.f) + 1e-5f);
        yb[tid] = (xz[tid] - m) * rstd * lw + lb;   // cn
      }
      __syncthreads();                     // cn in yb[0..160)
      {
        const float* cn = &yb[t_k * 40];
        float s = 0.f;
#pragma unroll
        for (int d = 0; d < 40; ++d) s += wkv[d] * cn[d];
        const int trow = c * CH + t_k;
        if (e_k < 40)
          __hip_atomic_store(&kbuf[trow * 40 + e_k], s, __ATOMIC_RELAXED,
                             __HIP_MEMORY_SCOPE_AGENT);
        else
          __hip_atomic_store(&vbuf[trow * 40 + (e_k - 40)], s,
                             __ATOMIC_RELAXED, __HIP_MEMORY_SCOPE_AGENT);
      }
      __syncthreads();                     // drain vmcnt (stores at IF$)
      if (tid == 0)
        __hip_atomic_store(kv_flag, c + 1, __ATOMIC_RELAXED,
                           __HIP_MEMORY_SCOPE_AGENT);
    }
    return;
  }

  // =================== LAYER BLOCKS (0..255): R8 loop, unchanged =========
  const int layer = blockIdx.x;

  const int e_in = tid % 160;
  const int tA = tid / 160;
  float w_in_r[40];                 // in_proj row with rmsnorm weight folded
  {
    const float4* g = (const float4*)(g_in_w + layer * 6400 + e_in * 40);
    const float4* nw = (const float4*)(g_norm_w + layer * 40);
#pragma unroll
    for (int k = 0; k < 10; ++k) {
      float4 v = g[k];
      float4 n = nw[k];
      w_in_r[4 * k] = v.x * n.x; w_in_r[4 * k + 1] = v.y * n.y;
      w_in_r[4 * k + 2] = v.z * n.z; w_in_r[4 * k + 3] = v.w * n.w;
    }
  }
  const int d_c = tid % 80;
  const int t_c = tid / 80;
  float cw[4]; float cb;
  {
    float4 v = *(const float4*)(g_conv_w + layer * 320 + d_c * 4);
    cw[0] = v.x; cw[1] = v.y; cw[2] = v.z; cw[3] = v.w;
    cb = g_conv_b[layer * 80 + d_c];
  }
  const int halfp = tid & 1;
  const int p_x = tid >> 1;              // <140 active for x_proj
  const int t_x = p_x / 35, e_x = p_x % 35;
  float w_xp_r[40];
  if (p_x < 140) {
    const float4* g = (const float4*)(g_xp_w + layer * 2800 + e_x * 80 + halfp * 40);
#pragma unroll
    for (int k = 0; k < 10; ++k) {
      float4 v = g[k];
      w_xp_r[4 * k] = v.x; w_xp_r[4 * k + 1] = v.y;
      w_xp_r[4 * k + 2] = v.z; w_xp_r[4 * k + 3] = v.w;
    }
  }
  const int d_ch = tid >> 2;
  const int qq = tid & 3;
  float negA[4], hst[4];
  {
    float4 v = *(const float4*)(g_alog + layer * 1280 + tid * 4);
    negA[0] = -__expf(v.x); negA[1] = -__expf(v.y);
    negA[2] = -__expf(v.z); negA[3] = -__expf(v.w);
    hst[0] = hst[1] = hst[2] = hst[3] = 0.f;
  }
  const float dtw0 = g_dt_w[layer * 240 + d_ch * 3 + 0];
  const float dtw1 = g_dt_w[layer * 240 + d_ch * 3 + 1];
  const float dtw2 = g_dt_w[layer * 240 + d_ch * 3 + 2];
  const float dtb = g_dt_b[layer * 80 + d_ch];
  const float wD = g_D[layer * 80 + d_ch];
  const int p_o = tid >> 1;
  const int t_o = p_o / 40, e_o = p_o % 40;
  float w_out_r[40];
  {
    const float4* g = (const float4*)(g_out_w + layer * 3200 + e_o * 80 + halfp * 40);
#pragma unroll
    for (int k = 0; k < 10; ++k) {
      float4 v = g[k];
      w_out_r[4 * k] = v.x; w_out_r[4 * k + 1] = v.y;
      w_out_r[4 * k + 2] = v.z; w_out_r[4 * k + 3] = v.w;
    }
  }

  for (int i = tid; i < 240; i += TPB1) xhist[i] = 0.f;
  __syncthreads();

  const float* src = (layer == 0) ? mash : ((layer & 1) ? xb0 : xb1);
  float* dst = (layer & 1) ? xb1 : xb0;
  int* flag_prev = flags + (layer - 1) * 32;
  int* flag_cur = flags + layer * 32;

  for (int c = 0; c < NCHUNK; ++c) {
    const int t0 = c * CH;

    // ---- Phase A: ordered acquire + in_proj (rmsnorm folded) ----
    if (layer == 0) {
#pragma unroll
      for (int tt = 0; tt < 2; ++tt) {
        const int t = tA + 2 * tt;
        const float4* sp = (const float4*)(src + (t0 + t) * 40);
        float ss = 0.f, sd = 0.f;
#pragma unroll
        for (int k = 0; k < 10; ++k) {
          float4 v = sp[k];
          ss += v.x * v.x + v.y * v.y + v.z * v.z + v.w * v.w;
          sd += w_in_r[4 * k] * v.x + w_in_r[4 * k + 1] * v.y
              + w_in_r[4 * k + 2] * v.z + w_in_r[4 * k + 3] * v.w;
        }
        xz[t * 160 + e_in] = sd * rsqrtf(ss * (1.f / 40.f) + 1e-5f);
      }
      if (tid < 160) xin[tid] = src[t0 * 40 + tid];
    } else {
      // every wave polls (wave-uniform); loads are program-ordered after the
      // observed flag -> guaranteed fresh (producer B5-drained before flag)
      while (__hip_atomic_load(flag_prev, __ATOMIC_RELAXED,
                               __HIP_MEMORY_SCOPE_AGENT) <= c)
        __builtin_amdgcn_s_sleep(1);
#pragma unroll
      for (int tt = 0; tt < 2; ++tt) {
        const int t = tA + 2 * tt;
        const u64* sp = (const u64*)(src + (t0 + t) * 40);
        float ss = 0.f, sd = 0.f;
#pragma unroll
        for (int k = 0; k < 20; ++k) {
          u64 a = __hip_atomic_load(sp + k, __ATOMIC_RELAXED,
                                    __HIP_MEMORY_SCOPE_AGENT);
          float v0 = unplo(a), v1 = unphi(a);
          ss += v0 * v0 + v1 * v1;
          sd += w_in_r[2 * k] * v0 + w_in_r[2 * k + 1] * v1;
        }
        xz[t * 160 + e_in] = sd * rsqrtf(ss * (1.f / 40.f) + 1e-5f);
      }
      if (tid < 80) {
        u64 a = __hip_atomic_load((const u64*)(src + t0 * 40) + tid,
                                  __ATOMIC_RELAXED, __HIP_MEMORY_SCOPE_AGENT);
        xin[2 * tid] = unplo(a);
        xin[2 * tid + 1] = unphi(a);
      }
    }
    __syncthreads();                                   // B1: xz, xin ready

    // ---- causal depthwise conv(4) + silu ----
    {
      float acc = cb;
#pragma unroll
      for (int j = 0; j < 4; ++j) {
        int lt = t_c - 3 + j;
        float xv = (lt >= 0) ? xz[lt * 160 + d_c] : xhist[(lt + 3) * 80 + d_c];
        acc += cw[j] * xv;
      }
      xs[t_c * 80 + d_c] = acc / (1.f + __expf(-acc));
    }
    __syncthreads();                                   // B2: xs ready

    // ---- x_proj: pair half-dots + shfl merge; idle threads refresh xhist ----
    if (p_x < 140) {
      const float4* xp = (const float4*)&xs[t_x * 80 + halfp * 40];
      float s = 0.f;
#pragma unroll
      for (int k = 0; k < 10; ++k) {
        float4 v = xp[k];
        s += w_xp_r[4 * k] * v.x + w_xp_r[4 * k + 1] * v.y
           + w_xp_r[4 * k + 2] * v.z + w_xp_r[4 * k + 3] * v.w;
      }
      s += __shfl_xor(s, 1);
      if (halfp == 0) dbc[t_x * 36 + e_x] = s;
    } else {
      for (int k = tid - 280; k < 240; k += 40)
        xhist[k] = xz[(1 + k / 80) * 160 + (k % 80)];
    }
    __syncthreads();                                   // B3: dbc ready

    // ---- selective scan; dt inline; state in regs ----
#pragma unroll
    for (int t = 0; t < CH; ++t) {
      const float* db = &dbc[t * 36];
      float sdt = dtb + db[0] * dtw0 + db[1] * dtw1 + db[2] * dtw2;
      float dtval = (sdt > 15.f) ? sdt : __logf(1.f + __expf(sdt));
      float xval = xs[t * 80 + d_ch];
      float part = 0.f;
#pragma unroll
      for (int j = 0; j < 4; ++j) {
        int s_i = qq * 4 + j;
        float Bv = db[3 + s_i];
        float Cv = db[19 + s_i];
        hst[j] = __expf(dtval * negA[j]) * hst[j] + dtval * Bv * xval;
        part += hst[j] * Cv;
      }
      part += __shfl_xor(part, 1);
      part += __shfl_xor(part, 2);
      if (qq == 0) {
        float yv = part + xval * wD;
        float z = xz[t * 160 + 80 + d_ch];
        yb[t * 80 + d_ch] = yv * z / (1.f + __expf(-z));
      }
    }
    __syncthreads();                                   // B4: yb ready

    // ---- out_proj + residual -> paired dwordx2 coherent stores ----
    {
      const float4* yp = (const float4*)&yb[t_o * 80 + halfp * 40];
      float s = 0.f;
#pragma unroll
      for (int k = 0; k < 10; ++k) {
        float4 v = yp[k];
        s += w_out_r[4 * k] * v.x + w_out_r[4 * k + 1] * v.y
           + w_out_r[4 * k + 2] * v.z + w_out_r[4 * k + 3] * v.w;
      }
      s += __shfl_xor(s, 1);
      float r = xin[p_o] + s;          // valid on pair leaders (halfp==0)
      float r2 = __shfl_xor(r, 2);     // leader tid+2's value (p_o+1)
      if ((tid & 3) == 0)              // even p_o leaders store the pair
        __hip_atomic_store((u64*)(dst + t0 * 40 + p_o), pack2(r, r2),
                           __ATOMIC_RELAXED, __HIP_MEMORY_SCOPE_AGENT);
    }
    __syncthreads();        // B5: drains vmcnt -> all stores acked at IF$
    if (tid == 0)
      __hip_atomic_store(flag_cur, c + 1, __ATOMIC_RELAXED,
                         __HIP_MEMORY_SCOPE_AGENT);
  }
}

extern "C" void kernel_launch(void* const* d_in, const int* in_sizes, int n_in,
                              void* d_out, int out_size, void* d_ws, size_t ws_size,
                              hipStream_t stream) {
  const float* mash   = (const float*)d_in[0];
  const float* qry    = (const float*)d_in[1];
  const float* lnw    = (const float*)d_in[2];
  const float* linw   = (const float*)d_in[3];
  const float* lconvw = (const float*)d_in[4];
  const float* lconvb = (const float*)d_in[5];
  const float* lxpw   = (const float*)d_in[6];
  const float* ldtw   = (const float*)d_in[7];
  const float* ldtb   = (const float*)d_in[8];
  const float* lAlog  = (const float*)d_in[9];
  const float* lD     = (const float*)d_in[10];
  const float* loutw  = (const float*)d_in[11];
  const float* pew    = (const float*)d_in[12];
  const float* peb    = (const float*)d_in[13];
  const float* lnqw   = (const float*)d_in[14];
  const float* lnqb   = (const float*)d_in[15];
  const float* lncw   = (const float*)d_in[16];
  const float* lncb   = (const float*)d_in[17];
  const float* qw     = (const float*)d_in[18];
  const float* kvw    = (const float*)d_in[19];
  const float* oww    = (const float*)d_in[20];
  const float* owb    = (const float*)d_in[21];
  const float* flnw   = (const float*)d_in[22];
  const float* flnb   = (const float*)d_in[23];
  const float* w1     = (const float*)d_in[24];
  const float* b1     = (const float*)d_in[25];
  const float* w2     = (const float*)d_in[26];
  const float* b2     = (const float*)d_in[27];
  const float* outw   = (const float*)d_in[28];
  const float* outb   = (const float*)d_in[29];

  // ws layout (f32): xb0[16000] xb1[16000] k[16000] v[16000]
  //                  flags[258*32 ints, 128B stride]
  float* wsf = (float*)d_ws;
  float* xb0 = wsf;
  float* xb1 = wsf + 16000;
  float* kbuf = wsf + 32000;
  float* vbuf = wsf + 48000;
  int* flags = (int*)(wsf + 64000);

  hipLaunchKernelGGL(init_flags, dim3(33), dim3(256), 0, stream, flags);
  hipLaunchKernelGGL(mamba_pipe, dim3(462), dim3(TPB1), 0, stream,
                     mash, lnw, linw, lconvw, lconvb, lxpw, ldtw, ldtb, lAlog,
                     lD, loutw, xb0, xb1, flags,
                     lncw, lncb, kvw, kbuf, vbuf,
                     qry, pew, peb, lnqw, lnqb, qw,
                     oww, owb, flnw, flnb, w1, b1, w2, b2, outw, outb,
                     (float*)d_out);
}